// Round 8
// baseline (73.636 us; speedup 1.0000x reference)
//
#include <hip/hip_runtime.h>
#include <hip/hip_bf16.h>

// Problem constants
#define B 64
#define S 512
#define D 768
#define K 8
#define R 277
#define NSPAN 10     // h, t, 8 bridge spans per batch
#define M_TOT 640    // pooled rows: [u: 0..63][v: 64..127][bi: 128..639]

// ---------------------------------------------------------------------------
// Pool phase 1: one block per (b, s-chunk). Span bounds scalarized via
// readfirstlane -> SGPRs, so the per-(row,span) guard is a scalar branch
// (no per-lane select cost). All RPC rows preloaded into registers with
// static indices (deep MLP, no scratch).
// ---------------------------------------------------------------------------
template<int RPC>
__global__ void k_pool1(const float* __restrict__ emb,
                        const int* __restrict__ h_span,
                        const int* __restrict__ t_span,
                        const int* __restrict__ b_spans,
                        float* __restrict__ partial) {
    int b = blockIdx.x, c = blockIdx.y;
    int nch = S / RPC;
    int r0 = c * RPC;
    int t = threadIdx.x;

    int s0[NSPAN], s1[NSPAN];
    s0[0] = __builtin_amdgcn_readfirstlane(h_span[b*2]);
    s1[0] = __builtin_amdgcn_readfirstlane(h_span[b*2+1]);
    s0[1] = __builtin_amdgcn_readfirstlane(t_span[b*2]);
    s1[1] = __builtin_amdgcn_readfirstlane(t_span[b*2+1]);
    #pragma unroll
    for (int k = 0; k < K; ++k) {
        s0[2+k] = __builtin_amdgcn_readfirstlane(b_spans[(b*K+k)*2]);
        s1[2+k] = __builtin_amdgcn_readfirstlane(b_spans[(b*K+k)*2 + 1]);
    }

    bool any = false;
    #pragma unroll
    for (int j = 0; j < NSPAN; ++j)
        any |= (s1[j] >= r0) && (s0[j] < r0 + RPC);
    if (!any) return;                       // scalar-uniform skip

    const float4* e4 = (const float4*)(emb + (size_t)b * S * D) + (size_t)r0 * (D/4) + t;
    float4 v[RPC];
    #pragma unroll
    for (int i = 0; i < RPC; ++i) v[i] = e4[i * (D/4)];   // static idx -> regs

    float4 m[NSPAN];
    #pragma unroll
    for (int j = 0; j < NSPAN; ++j)
        m[j] = make_float4(-INFINITY, -INFINITY, -INFINITY, -INFINITY);

    #pragma unroll
    for (int i = 0; i < RPC; ++i) {
        int s = r0 + i;
        #pragma unroll
        for (int j = 0; j < NSPAN; ++j) {
            if (s >= s0[j] && s <= s1[j]) {   // scalar branch (SGPR bounds)
                m[j].x = fmaxf(m[j].x, v[i].x); m[j].y = fmaxf(m[j].y, v[i].y);
                m[j].z = fmaxf(m[j].z, v[i].z); m[j].w = fmaxf(m[j].w, v[i].w);
            }
        }
    }

    #pragma unroll
    for (int j = 0; j < NSPAN; ++j) {
        if (s1[j] >= r0 && s0[j] < r0 + RPC) {
            *(float4*)(partial + (((size_t)(b*nch + c))*NSPAN + j) * D + t*4) = m[j];
        }
    }
}

// ---------------------------------------------------------------------------
// Pool phase 2: one block per (b, span j); reduce intersecting chunks.
// ---------------------------------------------------------------------------
__global__ void k_pool2(const float* __restrict__ partial,
                        const int* __restrict__ h_span,
                        const int* __restrict__ t_span,
                        const int* __restrict__ b_spans,
                        float* __restrict__ pooled, int rpc) {
    int task = blockIdx.x;
    int b = task / NSPAN, j = task % NSPAN;
    int s0, s1, row;
    if (j == 0)      { s0 = h_span[b*2]; s1 = h_span[b*2+1]; row = b; }
    else if (j == 1) { s0 = t_span[b*2]; s1 = t_span[b*2+1]; row = B + b; }
    else {
        int k = j - 2;
        s0 = b_spans[(b*K+k)*2]; s1 = b_spans[(b*K+k)*2 + 1];
        row = 2*B + b*K + k;
    }
    int nch = S / rpc;
    int c0 = s0 / rpc, c1 = s1 / rpc;
    int t = threadIdx.x;
    float4 m = make_float4(-INFINITY, -INFINITY, -INFINITY, -INFINITY);
    for (int c = c0; c <= c1; ++c) {
        float4 v = *(const float4*)(partial + (((size_t)(b*nch + c))*NSPAN + j) * D + t*4);
        m.x = fmaxf(m.x, v.x); m.y = fmaxf(m.y, v.y);
        m.z = fmaxf(m.z, v.z); m.w = fmaxf(m.w, v.w);
    }
    ((float4*)(pooled + (size_t)row * D))[t] = m;
}

// ---------------------------------------------------------------------------
// Shared 16-step LDS-tile FMA block (64x64 tile, 4x4 regs/thread).
// ---------------------------------------------------------------------------
__device__ __forceinline__
void tile_fma(const float (*At)[68], const float (*Wt)[68],
              int tx, int ty, float acc[4][4]) {
    #pragma unroll
    for (int dd = 0; dd < 16; ++dd) {
        float4 av  = *(const float4*)&At[dd][ty << 2];
        float4 wvv = *(const float4*)&Wt[dd][tx << 2];
        float a_[4] = {av.x, av.y, av.z, av.w};
        float w_[4] = {wvv.x, wvv.y, wvv.z, wvv.w};
        #pragma unroll
        for (int i = 0; i < 4; ++i)
            #pragma unroll
            for (int jj = 0; jj < 4; ++jj)
                acc[i][jj] += a_[i] * w_[jj];
    }
}

// ---------------------------------------------------------------------------
// Projection GEMM, prefetch-pipelined. grid (12, 10, KSPLIT), 256 thr.
// ---------------------------------------------------------------------------
template<int KSPLIT>
__global__ void k_gemm(const float* __restrict__ pooled,
                       const float* __restrict__ wu,
                       const float* __restrict__ wv,
                       const float* __restrict__ wi,
                       float* __restrict__ p_part) {
    __shared__ float At[16][68];
    __shared__ float Wt[16][68];
    int e0 = blockIdx.x * 64;
    int m0 = blockIdx.y * 64;
    const int klen = D / KSPLIT;
    int dbase = blockIdx.z * klen;
    const float* Wm = (m0 < B) ? wu : (m0 < 2*B) ? wv : wi;

    int tid = threadIdx.x;
    int tx = tid & 15, ty = tid >> 4;
    int lm = tid >> 2;
    int ld = (tid & 3) * 4;

    const float* arow = pooled + (size_t)(m0 + lm) * D + ld + dbase;
    const float* wrow = Wm     + (size_t)(e0 + lm) * D + ld + dbase;

    float acc[4][4] = {};
    const int NK = klen / 16;
    float4 a4 = *(const float4*)(arow);
    float4 w4 = *(const float4*)(wrow);
    for (int kc = 0; kc < NK; ++kc) {
        __syncthreads();
        At[ld+0][lm] = a4.x; At[ld+1][lm] = a4.y; At[ld+2][lm] = a4.z; At[ld+3][lm] = a4.w;
        Wt[ld+0][lm] = w4.x; Wt[ld+1][lm] = w4.y; Wt[ld+2][lm] = w4.z; Wt[ld+3][lm] = w4.w;
        __syncthreads();
        if (kc + 1 < NK) {
            a4 = *(const float4*)(arow + (kc+1)*16);
            w4 = *(const float4*)(wrow + (kc+1)*16);
        }
        tile_fma(At, Wt, tx, ty, acc);
    }
    #pragma unroll
    for (int i = 0; i < 4; ++i) {
        float4 o = make_float4(acc[i][0], acc[i][1], acc[i][2], acc[i][3]);
        *(float4*)(p_part + ((size_t)blockIdx.z * M_TOT + m0 + ty*4 + i) * D + e0 + tx*4) = o;
    }
}

// ---------------------------------------------------------------------------
// Attention: reduce partials+bias -> U,V,BI; dots; softmax; s = U+V+ctx.
// ALSO initializes out[b][:] = pred_b (predg atomically accumulates later).
// ---------------------------------------------------------------------------
template<int KSPLIT>
__global__ __launch_bounds__(512)
void k_att2(const float* __restrict__ p_part,
            const float* __restrict__ wu_b,
            const float* __restrict__ wv_b,
            const float* __restrict__ wi_b,
            const float* __restrict__ pred_b,
            float* __restrict__ s_out,
            float* __restrict__ out) {
    __shared__ float U[D], V[D], BI[K][D];
    __shared__ float dots[K];
    int b = blockIdx.x, tid = threadIdx.x;

    // out init (independent of the rest; no sync needed before end)
    for (int r = tid; r < R; r += 512) out[(size_t)b * R + r] = pred_b[r];

    for (int task = tid; task < NSPAN * (D/4); task += 512) {
        int j = task / (D/4), sl = task % (D/4);
        size_t row = (j == 0) ? (size_t)b : (j == 1) ? (size_t)(B + b)
                   : (size_t)(2*B + b*K + (j - 2));
        const float* bias = (j == 0) ? wu_b : (j == 1) ? wv_b : wi_b;
        float4 acc = *(const float4*)(bias + sl*4);
        #pragma unroll
        for (int ks = 0; ks < KSPLIT; ++ks) {
            float4 p = *(const float4*)(p_part + ((size_t)ks * M_TOT + row) * D + sl*4);
            acc.x += p.x; acc.y += p.y; acc.z += p.z; acc.w += p.w;
        }
        float* dst = (j == 0) ? U : (j == 1) ? V : BI[j-2];
        *(float4*)(dst + sl*4) = acc;
    }
    __syncthreads();

    int wave = tid >> 6, lane = tid & 63;
    {
        float part = 0.f;
        #pragma unroll
        for (int i = 0; i < D/64; ++i) {
            int d = i*64 + lane;
            part += U[d] * BI[wave][d];
        }
        #pragma unroll
        for (int off = 32; off > 0; off >>= 1) part += __shfl_xor(part, off);
        if (lane == 0) dots[wave] = part * 0.125f;   // 1/sqrt(D_K=64)
    }
    __syncthreads();

    float mx = -INFINITY;
    #pragma unroll
    for (int k = 0; k < K; ++k) mx = fmaxf(mx, dots[k]);
    float ex[K], sum = 0.f;
    #pragma unroll
    for (int k = 0; k < K; ++k) { ex[k] = expf(dots[k] - mx); sum += ex[k]; }
    float inv = 1.f / sum;
    for (int d = tid; d < D; d += 512) {
        float c = 0.f;
        #pragma unroll
        for (int k = 0; k < K; ++k) c += ex[k] * BI[k][d];
        s_out[(size_t)b * D + d] = U[d] + V[d] + c * inv;
    }
}

// ---------------------------------------------------------------------------
// pair GEMM partials, pipelined: grid (12, KS=8), 256 thr.
// ---------------------------------------------------------------------------
template<int KS>
__global__ void k_pairg(const float* __restrict__ s,
                        const float* __restrict__ ln1_w,
                        float* __restrict__ pair_part) {
    __shared__ float At[16][68];
    __shared__ float Wt[16][68];
    int e0 = blockIdx.x * 64;
    int dbase = blockIdx.y * (D / KS);

    int tid = threadIdx.x;
    int tx = tid & 15, ty = tid >> 4;
    int lm = tid >> 2;
    int ld = (tid & 3) * 4;

    const float* arow = s     + (size_t)lm * D + ld + dbase;
    const float* wrow = ln1_w + (size_t)(e0 + lm) * D + ld + dbase;

    float acc[4][4] = {};
    const int NK = (D/KS) / 16;
    float4 a4 = *(const float4*)(arow);
    float4 w4 = *(const float4*)(wrow);
    for (int kc = 0; kc < NK; ++kc) {
        __syncthreads();
        At[ld+0][lm] = a4.x; At[ld+1][lm] = a4.y; At[ld+2][lm] = a4.z; At[ld+3][lm] = a4.w;
        Wt[ld+0][lm] = w4.x; Wt[ld+1][lm] = w4.y; Wt[ld+2][lm] = w4.z; Wt[ld+3][lm] = w4.w;
        __syncthreads();
        if (kc + 1 < NK) {
            a4 = *(const float4*)(arow + (kc+1)*16);
            w4 = *(const float4*)(wrow + (kc+1)*16);
        }
        tile_fma(At, Wt, tx, ty, acc);
    }
    #pragma unroll
    for (int i = 0; i < 4; ++i) {
        float4 o = make_float4(acc[i][0], acc[i][1], acc[i][2], acc[i][3]);
        *(float4*)(pair_part + ((size_t)blockIdx.y * B + ty*4 + i) * D + e0 + tx*4) = o;
    }
}

// ---------------------------------------------------------------------------
// pred GEMM: A = relu(sum_ks pair_part + ln1_b) built on the fly (pipelined),
// result atomically accumulated into out (pre-initialized with pred_b by
// k_att2). grid (ceil(R/64)=5, KSP=8), 256 thr.
// ---------------------------------------------------------------------------
template<int KSP, int KSPAIR>
__global__ void k_predg(const float* __restrict__ pair_part,
                        const float* __restrict__ ln1_b,
                        const float* __restrict__ pred_w,
                        float* __restrict__ out) {
    __shared__ float At[16][68];
    __shared__ float Wt[16][68];
    int r0 = blockIdx.x * 64;
    int dbase = blockIdx.y * (D / KSP);

    int tid = threadIdx.x;
    int tx = tid & 15, ty = tid >> 4;
    int lm = tid >> 2;
    int ld = (tid & 3) * 4;

    int rw = r0 + lm; if (rw >= R) rw = R - 1;     // clamp weight row (pad)
    const float* prow = pair_part + (size_t)lm * D + ld + dbase;   // + ks*B*D
    const float* wrow = pred_w + (size_t)rw * D + ld + dbase;

    auto build_a = [&](int kc) -> float4 {
        float4 a = *(const float4*)(ln1_b + dbase + kc*16 + ld);
        #pragma unroll
        for (int ks = 0; ks < KSPAIR; ++ks) {
            float4 p = *(const float4*)(prow + (size_t)ks * B * D + kc*16);
            a.x += p.x; a.y += p.y; a.z += p.z; a.w += p.w;
        }
        a.x = fmaxf(a.x, 0.f); a.y = fmaxf(a.y, 0.f);
        a.z = fmaxf(a.z, 0.f); a.w = fmaxf(a.w, 0.f);
        return a;
    };

    float acc[4][4] = {};
    const int NK = (D/KSP) / 16;
    float4 a4 = build_a(0);
    float4 w4 = *(const float4*)(wrow);
    for (int kc = 0; kc < NK; ++kc) {
        __syncthreads();
        At[ld+0][lm] = a4.x; At[ld+1][lm] = a4.y; At[ld+2][lm] = a4.z; At[ld+3][lm] = a4.w;
        Wt[ld+0][lm] = w4.x; Wt[ld+1][lm] = w4.y; Wt[ld+2][lm] = w4.z; Wt[ld+3][lm] = w4.w;
        __syncthreads();
        if (kc + 1 < NK) {
            a4 = build_a(kc+1);
            w4 = *(const float4*)(wrow + (kc+1)*16);
        }
        tile_fma(At, Wt, tx, ty, acc);
    }
    // atomic epilogue: out[m][r] += acc ; m = batch, r = pred row
    #pragma unroll
    for (int i = 0; i < 4; ++i) {
        int m = ty*4 + i;
        #pragma unroll
        for (int jj = 0; jj < 4; ++jj) {
            int r = r0 + tx*4 + jj;
            if (r < R) atomicAdd(&out[(size_t)m * R + r], acc[i][jj]);
        }
    }
}

// ---------------------------------------------------------------------------
extern "C" void kernel_launch(void* const* d_in, const int* in_sizes, int n_in,
                              void* d_out, int out_size, void* d_ws, size_t ws_size,
                              hipStream_t stream) {
    const float* emb     = (const float*)d_in[0];
    const int*   h_span  = (const int*)  d_in[1];
    const int*   t_span  = (const int*)  d_in[2];
    const int*   b_spans = (const int*)  d_in[3];
    const float* wu_w    = (const float*)d_in[4];
    const float* wu_b    = (const float*)d_in[5];
    const float* wv_w    = (const float*)d_in[6];
    const float* wv_b    = (const float*)d_in[7];
    const float* wi_w    = (const float*)d_in[8];
    const float* wi_b    = (const float*)d_in[9];
    const float* ln1_w   = (const float*)d_in[10];
    const float* ln1_b   = (const float*)d_in[11];
    const float* pred_w  = (const float*)d_in[12];
    const float* pred_b  = (const float*)d_in[13];
    float* out = (float*)d_out;

    const int KSPLIT = 4;   // projection GEMM k-split
    const int KS     = 8;   // pair/pred GEMM k-split
    const int NCH    = 32;  // pool chunks (RPC=16)

    float* ws        = (float*)d_ws;
    float* pooled    = ws;                                     // M_TOT*D
    float* p_part    = pooled    + (size_t)M_TOT * D;          // KSPLIT*M_TOT*D
    float* s_buf     = p_part    + (size_t)KSPLIT * M_TOT * D; // B*D
    float* pair_part = s_buf     + (size_t)B * D;              // KS*B*D
    float* partial   = pair_part + (size_t)KS * B * D;         // B*NCH*NSPAN*D
    (void)ws_size; (void)in_sizes; (void)n_in; (void)out_size; // 74 MB << ws

    k_pool1<S/NCH><<<dim3(B, NCH), 192, 0, stream>>>(emb, h_span, t_span, b_spans, partial);
    k_pool2<<<M_TOT, 192, 0, stream>>>(partial, h_span, t_span, b_spans, pooled, S / NCH);
    k_gemm<KSPLIT><<<dim3(D/64, M_TOT/64, KSPLIT), 256, 0, stream>>>(pooled, wu_w, wv_w, wi_w, p_part);
    k_att2<KSPLIT><<<B, 512, 0, stream>>>(p_part, wu_b, wv_b, wi_b, pred_b, s_buf, out);
    k_pairg<KS><<<dim3(D/64, KS), 256, 0, stream>>>(s_buf, ln1_w, pair_part);
    k_predg<KS, KS><<<dim3((R+63)/64, KS), 256, 0, stream>>>(pair_part, ln1_b, pred_w, out);
}

// Round 9
// 69.047 us; speedup vs baseline: 1.0665x; 1.0665x over previous
//
#include <hip/hip_runtime.h>
#include <hip/hip_bf16.h>

// Problem constants
#define B 64
#define S 512
#define D 768
#define K 8
#define R 277
#define NSPAN 10     // h, t, 8 bridge spans per batch
#define M_TOT 640    // pooled rows: [u: 0..63][v: 64..127][bi: 128..639]

typedef unsigned short ushort_t;
typedef __attribute__((ext_vector_type(8))) short short8;
typedef __attribute__((ext_vector_type(4))) float f32x4;

__device__ __forceinline__ ushort_t f2bf(float f) {
    unsigned u = __float_as_uint(f);
    unsigned r = (u + 0x7FFFu + ((u >> 16) & 1u)) >> 16;   // RNE
    return (ushort_t)r;
}

// ---------------------------------------------------------------------------
// Pool phase 1 (R7 form: streaming, branchless select): one block per
// (b, s-chunk); RPC rows fully unrolled for deep MLP.
// ---------------------------------------------------------------------------
template<int RPC>
__global__ void k_pool1(const float* __restrict__ emb,
                        const int* __restrict__ h_span,
                        const int* __restrict__ t_span,
                        const int* __restrict__ b_spans,
                        float* __restrict__ partial) {
    int b = blockIdx.x, c = blockIdx.y;
    int nch = S / RPC;
    int r0 = c * RPC;
    int t = threadIdx.x;

    int s0[NSPAN], s1[NSPAN];
    s0[0] = h_span[b*2]; s1[0] = h_span[b*2+1];
    s0[1] = t_span[b*2]; s1[1] = t_span[b*2+1];
    #pragma unroll
    for (int k = 0; k < K; ++k) {
        s0[2+k] = b_spans[(b*K+k)*2];
        s1[2+k] = b_spans[(b*K+k)*2 + 1];
    }

    bool any = false;
    #pragma unroll
    for (int j = 0; j < NSPAN; ++j)
        any |= (s1[j] >= r0) && (s0[j] < r0 + RPC);
    if (!any) return;

    float4 m[NSPAN];
    #pragma unroll
    for (int j = 0; j < NSPAN; ++j)
        m[j] = make_float4(-INFINITY, -INFINITY, -INFINITY, -INFINITY);

    const float4* e4 = (const float4*)(emb + (size_t)b * S * D) + (size_t)r0 * (D/4) + t;
    #pragma unroll
    for (int i = 0; i < RPC; ++i) {
        float4 v = e4[i * (D/4)];
        int s = r0 + i;
        #pragma unroll
        for (int j = 0; j < NSPAN; ++j) {
            bool in = (s >= s0[j]) && (s <= s1[j]);
            float vx = in ? v.x : -INFINITY;
            float vy = in ? v.y : -INFINITY;
            float vz = in ? v.z : -INFINITY;
            float vw = in ? v.w : -INFINITY;
            m[j].x = fmaxf(m[j].x, vx); m[j].y = fmaxf(m[j].y, vy);
            m[j].z = fmaxf(m[j].z, vz); m[j].w = fmaxf(m[j].w, vw);
        }
    }

    #pragma unroll
    for (int j = 0; j < NSPAN; ++j) {
        if (s1[j] >= r0 && s0[j] < r0 + RPC) {
            *(float4*)(partial + (((size_t)(b*nch + c))*NSPAN + j) * D + t*4) = m[j];
        }
    }
}

// ---------------------------------------------------------------------------
// Pool phase 2: reduce intersecting chunks; writes pooled as BF16 (GEMM input).
// ---------------------------------------------------------------------------
__global__ void k_pool2(const float* __restrict__ partial,
                        const int* __restrict__ h_span,
                        const int* __restrict__ t_span,
                        const int* __restrict__ b_spans,
                        ushort_t* __restrict__ pooled_bf, int rpc) {
    int task = blockIdx.x;
    int b = task / NSPAN, j = task % NSPAN;
    int s0, s1, row;
    if (j == 0)      { s0 = h_span[b*2]; s1 = h_span[b*2+1]; row = b; }
    else if (j == 1) { s0 = t_span[b*2]; s1 = t_span[b*2+1]; row = B + b; }
    else {
        int k = j - 2;
        s0 = b_spans[(b*K+k)*2]; s1 = b_spans[(b*K+k)*2 + 1];
        row = 2*B + b*K + k;
    }
    int nch = S / rpc;
    int c0 = s0 / rpc, c1 = s1 / rpc;
    int t = threadIdx.x;
    float4 m = make_float4(-INFINITY, -INFINITY, -INFINITY, -INFINITY);
    for (int c = c0; c <= c1; ++c) {
        float4 v = *(const float4*)(partial + (((size_t)(b*nch + c))*NSPAN + j) * D + t*4);
        m.x = fmaxf(m.x, v.x); m.y = fmaxf(m.y, v.y);
        m.z = fmaxf(m.z, v.z); m.w = fmaxf(m.w, v.w);
    }
    unsigned lo = (unsigned)f2bf(m.x) | ((unsigned)f2bf(m.y) << 16);
    unsigned hi = (unsigned)f2bf(m.z) | ((unsigned)f2bf(m.w) << 16);
    *(uint2*)&pooled_bf[(size_t)row * D + t*4] = make_uint2(lo, hi);
}

// ---------------------------------------------------------------------------
// Weight conversion fp32 -> bf16: wbf = [wu | wv | wi], each [D][D].
// Thread handles 8 elements. grid = 3*D*D/(256*8) = 864 blocks.
// ---------------------------------------------------------------------------
__global__ void k_cvt(const float* __restrict__ wu,
                      const float* __restrict__ wv,
                      const float* __restrict__ wi,
                      ushort_t* __restrict__ wbf) {
    int g = blockIdx.x * 256 + threadIdx.x;
    const int per = (D*D) / 8;
    const float* src = (g < per) ? wu : (g < 2*per) ? wv : wi;
    int lg = g - ((g < per) ? 0 : (g < 2*per) ? per : 2*per);
    float4 f0 = *(const float4*)(src + (size_t)lg*8);
    float4 f1 = *(const float4*)(src + (size_t)lg*8 + 4);
    short8 o;
    o[0] = (short)f2bf(f0.x); o[1] = (short)f2bf(f0.y);
    o[2] = (short)f2bf(f0.z); o[3] = (short)f2bf(f0.w);
    o[4] = (short)f2bf(f1.x); o[5] = (short)f2bf(f1.y);
    o[6] = (short)f2bf(f1.z); o[7] = (short)f2bf(f1.w);
    *(short8*)&wbf[(size_t)g * 8] = o;
}

// ---------------------------------------------------------------------------
// Projection GEMM via bf16 MFMA 16x16x32. Tile 64(M)x64(E), BK=64, 4 waves;
// wave w computes rows m0+w*16..+15 x all 64 cols (4 n-subtiles).
// LDS XOR-swizzled (chunk ^= row&7) to avoid the 128B-row-stride conflict.
// A = pooled_bf[m][d]; B[k=d][n=e] = W[e][d] -> stage W rows as-is.
// grid (12, 10, KSPLIT=2), 256 thr. Output p_part fp32.
// ---------------------------------------------------------------------------
template<int KSPLIT>
__global__ __launch_bounds__(256)
void k_gemm_bf(const ushort_t* __restrict__ abf,
               const ushort_t* __restrict__ wbf,
               float* __restrict__ p_part) {
    __shared__ ushort_t Al[64][64];   // [m][k] 8KB, 16B-chunk-swizzled
    __shared__ ushort_t Bl[64][64];   // [e][k] 8KB
    int e0 = blockIdx.x * 64;
    int m0 = blockIdx.y * 64;
    int dbase = blockIdx.z * (D / KSPLIT);
    const ushort_t* Wm = wbf + (size_t)((m0 < B) ? 0 : (m0 < 2*B) ? 1 : 2) * D * D;

    int tid = threadIdx.x;
    int w = tid >> 6, l = tid & 63;
    int srow = tid >> 2;              // staging row 0..63
    int sc   = tid & 3;               // staging chunk 0..3 (and +4)

    const ushort_t* ga = abf + (size_t)(m0 + srow) * D + dbase;
    const ushort_t* gb = Wm  + (size_t)(e0 + srow) * D + dbase;
    int p0 = ((sc     ) ^ (srow & 7)) * 8;   // swizzled elem offsets
    int p1 = ((sc + 4 ) ^ (srow & 7)) * 8;

    f32x4 acc[4] = {};
    const int NIT = (D / KSPLIT) / 64;       // 6
    short8 pa0 = *(const short8*)(ga + sc*8);
    short8 pa1 = *(const short8*)(ga + sc*8 + 32);
    short8 pb0 = *(const short8*)(gb + sc*8);
    short8 pb1 = *(const short8*)(gb + sc*8 + 32);

    for (int it = 0; it < NIT; ++it) {
        __syncthreads();
        *(short8*)&Al[srow][p0] = pa0;
        *(short8*)&Al[srow][p1] = pa1;
        *(short8*)&Bl[srow][p0] = pb0;
        *(short8*)&Bl[srow][p1] = pb1;
        __syncthreads();
        if (it + 1 < NIT) {
            ga += 64; gb += 64;
            pa0 = *(const short8*)(ga + sc*8);
            pa1 = *(const short8*)(ga + sc*8 + 32);
            pb0 = *(const short8*)(gb + sc*8);
            pb1 = *(const short8*)(gb + sc*8 + 32);
        }
        int g = l >> 4, x = l & 7;
        #pragma unroll
        for (int ks = 0; ks < 2; ++ks) {
            int chunk = ks*4 + g;
            short8 a = *(const short8*)&Al[w*16 + (l & 15)][(chunk ^ x) * 8];
            #pragma unroll
            for (int nt = 0; nt < 4; ++nt) {
                short8 bf = *(const short8*)&Bl[nt*16 + (l & 15)][(chunk ^ x) * 8];
                acc[nt] = __builtin_amdgcn_mfma_f32_16x16x32_bf16(a, bf, acc[nt], 0, 0, 0);
            }
        }
    }

    int r4 = (l >> 4) * 4, cc = l & 15;
    #pragma unroll
    for (int nt = 0; nt < 4; ++nt)
        #pragma unroll
        for (int r = 0; r < 4; ++r)
            p_part[((size_t)blockIdx.z * M_TOT + m0 + w*16 + r4 + r) * D + e0 + nt*16 + cc] = acc[nt][r];
}

// ---------------------------------------------------------------------------
// Attention: reduce partials+bias -> U,V,BI; dots; softmax; s = U+V+ctx.
// Also initializes out[b][:] = pred_b (predg atomically accumulates later).
// ---------------------------------------------------------------------------
template<int KSPLIT>
__global__ __launch_bounds__(512)
void k_att2(const float* __restrict__ p_part,
            const float* __restrict__ wu_b,
            const float* __restrict__ wv_b,
            const float* __restrict__ wi_b,
            const float* __restrict__ pred_b,
            float* __restrict__ s_out,
            float* __restrict__ out) {
    __shared__ float U[D], V[D], BI[K][D];
    __shared__ float dots[K];
    int b = blockIdx.x, tid = threadIdx.x;

    for (int r = tid; r < R; r += 512) out[(size_t)b * R + r] = pred_b[r];

    for (int task = tid; task < NSPAN * (D/4); task += 512) {
        int j = task / (D/4), sl = task % (D/4);
        size_t row = (j == 0) ? (size_t)b : (j == 1) ? (size_t)(B + b)
                   : (size_t)(2*B + b*K + (j - 2));
        const float* bias = (j == 0) ? wu_b : (j == 1) ? wv_b : wi_b;
        float4 acc = *(const float4*)(bias + sl*4);
        #pragma unroll
        for (int ks = 0; ks < KSPLIT; ++ks) {
            float4 p = *(const float4*)(p_part + ((size_t)ks * M_TOT + row) * D + sl*4);
            acc.x += p.x; acc.y += p.y; acc.z += p.z; acc.w += p.w;
        }
        float* dst = (j == 0) ? U : (j == 1) ? V : BI[j-2];
        *(float4*)(dst + sl*4) = acc;
    }
    __syncthreads();

    int wave = tid >> 6, lane = tid & 63;
    {
        float part = 0.f;
        #pragma unroll
        for (int i = 0; i < D/64; ++i) {
            int d = i*64 + lane;
            part += U[d] * BI[wave][d];
        }
        #pragma unroll
        for (int off = 32; off > 0; off >>= 1) part += __shfl_xor(part, off);
        if (lane == 0) dots[wave] = part * 0.125f;   // 1/sqrt(D_K=64)
    }
    __syncthreads();

    float mx = -INFINITY;
    #pragma unroll
    for (int k = 0; k < K; ++k) mx = fmaxf(mx, dots[k]);
    float ex[K], sum = 0.f;
    #pragma unroll
    for (int k = 0; k < K; ++k) { ex[k] = expf(dots[k] - mx); sum += ex[k]; }
    float inv = 1.f / sum;
    for (int d = tid; d < D; d += 512) {
        float c = 0.f;
        #pragma unroll
        for (int k = 0; k < K; ++k) c += ex[k] * BI[k][d];
        s_out[(size_t)b * D + d] = U[d] + V[d] + c * inv;
    }
}

// ---------------------------------------------------------------------------
// Shared fp32 LDS-tile FMA (64x64, 4x4/thread) for the small tail GEMMs.
// ---------------------------------------------------------------------------
__device__ __forceinline__
void tile_fma(const float (*At)[68], const float (*Wt)[68],
              int tx, int ty, float acc[4][4]) {
    #pragma unroll
    for (int dd = 0; dd < 16; ++dd) {
        float4 av  = *(const float4*)&At[dd][ty << 2];
        float4 wvv = *(const float4*)&Wt[dd][tx << 2];
        float a_[4] = {av.x, av.y, av.z, av.w};
        float w_[4] = {wvv.x, wvv.y, wvv.z, wvv.w};
        #pragma unroll
        for (int i = 0; i < 4; ++i)
            #pragma unroll
            for (int jj = 0; jj < 4; ++jj)
                acc[i][jj] += a_[i] * w_[jj];
    }
}

// ---------------------------------------------------------------------------
// pair GEMM partials, pipelined: grid (12, KS=8), 256 thr.
// ---------------------------------------------------------------------------
template<int KS>
__global__ void k_pairg(const float* __restrict__ s,
                        const float* __restrict__ ln1_w,
                        float* __restrict__ pair_part) {
    __shared__ float At[16][68];
    __shared__ float Wt[16][68];
    int e0 = blockIdx.x * 64;
    int dbase = blockIdx.y * (D / KS);

    int tid = threadIdx.x;
    int tx = tid & 15, ty = tid >> 4;
    int lm = tid >> 2;
    int ld = (tid & 3) * 4;

    const float* arow = s     + (size_t)lm * D + ld + dbase;
    const float* wrow = ln1_w + (size_t)(e0 + lm) * D + ld + dbase;

    float acc[4][4] = {};
    const int NK = (D/KS) / 16;
    float4 a4 = *(const float4*)(arow);
    float4 w4 = *(const float4*)(wrow);
    for (int kc = 0; kc < NK; ++kc) {
        __syncthreads();
        At[ld+0][lm] = a4.x; At[ld+1][lm] = a4.y; At[ld+2][lm] = a4.z; At[ld+3][lm] = a4.w;
        Wt[ld+0][lm] = w4.x; Wt[ld+1][lm] = w4.y; Wt[ld+2][lm] = w4.z; Wt[ld+3][lm] = w4.w;
        __syncthreads();
        if (kc + 1 < NK) {
            a4 = *(const float4*)(arow + (kc+1)*16);
            w4 = *(const float4*)(wrow + (kc+1)*16);
        }
        tile_fma(At, Wt, tx, ty, acc);
    }
    #pragma unroll
    for (int i = 0; i < 4; ++i) {
        float4 o = make_float4(acc[i][0], acc[i][1], acc[i][2], acc[i][3]);
        *(float4*)(pair_part + ((size_t)blockIdx.y * B + ty*4 + i) * D + e0 + tx*4) = o;
    }
}

// ---------------------------------------------------------------------------
// pred GEMM: A = relu(sum_ks pair_part + ln1_b) built on the fly, atomic
// accumulate into out. grid (5, KSP=8), 256 thr.
// ---------------------------------------------------------------------------
template<int KSP, int KSPAIR>
__global__ void k_predg(const float* __restrict__ pair_part,
                        const float* __restrict__ ln1_b,
                        const float* __restrict__ pred_w,
                        float* __restrict__ out) {
    __shared__ float At[16][68];
    __shared__ float Wt[16][68];
    int r0 = blockIdx.x * 64;
    int dbase = blockIdx.y * (D / KSP);

    int tid = threadIdx.x;
    int tx = tid & 15, ty = tid >> 4;
    int lm = tid >> 2;
    int ld = (tid & 3) * 4;

    int rw = r0 + lm; if (rw >= R) rw = R - 1;
    const float* prow = pair_part + (size_t)lm * D + ld + dbase;
    const float* wrow = pred_w + (size_t)rw * D + ld + dbase;

    auto build_a = [&](int kc) -> float4 {
        float4 a = *(const float4*)(ln1_b + dbase + kc*16 + ld);
        #pragma unroll
        for (int ks = 0; ks < KSPAIR; ++ks) {
            float4 p = *(const float4*)(prow + (size_t)ks * B * D + kc*16);
            a.x += p.x; a.y += p.y; a.z += p.z; a.w += p.w;
        }
        a.x = fmaxf(a.x, 0.f); a.y = fmaxf(a.y, 0.f);
        a.z = fmaxf(a.z, 0.f); a.w = fmaxf(a.w, 0.f);
        return a;
    };

    float acc[4][4] = {};
    const int NK = (D/KSP) / 16;
    float4 a4 = build_a(0);
    float4 w4 = *(const float4*)(wrow);
    for (int kc = 0; kc < NK; ++kc) {
        __syncthreads();
        At[ld+0][lm] = a4.x; At[ld+1][lm] = a4.y; At[ld+2][lm] = a4.z; At[ld+3][lm] = a4.w;
        Wt[ld+0][lm] = w4.x; Wt[ld+1][lm] = w4.y; Wt[ld+2][lm] = w4.z; Wt[ld+3][lm] = w4.w;
        __syncthreads();
        if (kc + 1 < NK) {
            a4 = build_a(kc+1);
            w4 = *(const float4*)(wrow + (kc+1)*16);
        }
        tile_fma(At, Wt, tx, ty, acc);
    }
    #pragma unroll
    for (int i = 0; i < 4; ++i) {
        int m = ty*4 + i;
        #pragma unroll
        for (int jj = 0; jj < 4; ++jj) {
            int r = r0 + tx*4 + jj;
            if (r < R) atomicAdd(&out[(size_t)m * R + r], acc[i][jj]);
        }
    }
}

// ---------------------------------------------------------------------------
extern "C" void kernel_launch(void* const* d_in, const int* in_sizes, int n_in,
                              void* d_out, int out_size, void* d_ws, size_t ws_size,
                              hipStream_t stream) {
    const float* emb     = (const float*)d_in[0];
    const int*   h_span  = (const int*)  d_in[1];
    const int*   t_span  = (const int*)  d_in[2];
    const int*   b_spans = (const int*)  d_in[3];
    const float* wu_w    = (const float*)d_in[4];
    const float* wu_b    = (const float*)d_in[5];
    const float* wv_w    = (const float*)d_in[6];
    const float* wv_b    = (const float*)d_in[7];
    const float* wi_w    = (const float*)d_in[8];
    const float* wi_b    = (const float*)d_in[9];
    const float* ln1_w   = (const float*)d_in[10];
    const float* ln1_b   = (const float*)d_in[11];
    const float* pred_w  = (const float*)d_in[12];
    const float* pred_b  = (const float*)d_in[13];
    float* out = (float*)d_out;

    const int KSPLIT = 2;   // projection GEMM k-split
    const int KS     = 8;   // pair/pred GEMM k-split
    const int NCH    = 32;  // pool chunks (RPC=16)

    float* ws = (float*)d_ws;
    ushort_t* pooled_bf = (ushort_t*)ws;                          // M_TOT*D bf16 (=245,760 fl)
    ushort_t* wbf   = (ushort_t*)(ws + (size_t)M_TOT*D/2);        // 3*D*D bf16 (=884,736 fl)
    float* p_part    = ws + (size_t)M_TOT*D/2 + (size_t)3*D*D/2;  // KSPLIT*M_TOT*D
    float* s_buf     = p_part + (size_t)KSPLIT * M_TOT * D;       // B*D
    float* pair_part = s_buf + (size_t)B * D;                     // KS*B*D
    float* partial   = pair_part + (size_t)KS * B * D;            // B*NCH*NSPAN*D
    (void)ws_size; (void)in_sizes; (void)n_in; (void)out_size;

    k_pool1<S/NCH><<<dim3(B, NCH), 192, 0, stream>>>(emb, h_span, t_span, b_spans, partial);
    k_cvt<<<3*D*D/(256*8), 256, 0, stream>>>(wu_w, wv_w, wi_w, wbf);
    k_pool2<<<M_TOT, 192, 0, stream>>>(partial, h_span, t_span, b_spans, pooled_bf, S / NCH);
    k_gemm_bf<KSPLIT><<<dim3(D/64, M_TOT/64, KSPLIT), 256, 0, stream>>>(pooled_bf, wbf, p_part);
    k_att2<KSPLIT><<<B, 512, 0, stream>>>(p_part, wu_b, wv_b, wi_b, pred_b, s_buf, out);
    k_pairg<KS><<<dim3(D/64, KS), 256, 0, stream>>>(s_buf, ln1_w, pair_part);
    k_predg<KS, KS><<<dim3((R+63)/64, KS), 256, 0, stream>>>(pair_part, ln1_b, pred_w, out);
}